// Round 8
// baseline (54.216 us; speedup 1.0000x reference)
//
#include <hip/hip_runtime.h>

#define NN   30000
#define NCTX 32
#define FIN  256
#define HID  128

typedef short short8 __attribute__((ext_vector_type(8)));
typedef float f32x4  __attribute__((ext_vector_type(4)));

__device__ __forceinline__ unsigned short f2b(float x) {   // RTNE
    union { float f; unsigned u; } v; v.f = x;
    unsigned r = v.u + 0x7FFFu + ((v.u >> 16) & 1u);
    return (unsigned short)(r >> 16);
}
__device__ __forceinline__ unsigned short f2b_trunc(float x) {
    union { float f; unsigned u; } v; v.f = x;
    return (unsigned short)(v.u >> 16);
}
__device__ __forceinline__ float b2f(unsigned short u) {
    union { unsigned u; float f; } v; v.u = ((unsigned)u) << 16;
    return v.f;
}

// Blocks 0-63: pack W_j into MFMA B-fragment order (split bf16 hi/lo).
// Blocks 64-127: vi[f] = Wi[f,:].aw  (quarter-wave per feature, coalesced).
__global__ __launch_bounds__(64) void k_pack(const float* __restrict__ Wj,
                                             const float* __restrict__ Wi,
                                             const float* __restrict__ aw,
                                             short8* __restrict__ whi,
                                             short8* __restrict__ wlo,
                                             float* __restrict__ vi) {
    const int b = blockIdx.x;
    const int l = threadIdx.x;
    if (b >= 64) {
        const int fi = l >> 4;
        const int q  = l & 15;
        const int f  = (b - 64) * 4 + fi;
        const float4 w0 = *(const float4*)(Wi + (long)f * HID + q * 8);
        const float4 w1 = *(const float4*)(Wi + (long)f * HID + q * 8 + 4);
        const float4 a0 = *(const float4*)(aw + q * 8);
        const float4 a1 = *(const float4*)(aw + q * 8 + 4);
        float s = w0.x * a0.x + w0.y * a0.y + w0.z * a0.z + w0.w * a0.w
                + w1.x * a1.x + w1.y * a1.y + w1.z * a1.z + w1.w * a1.w;
        s += __shfl_xor(s, 1); s += __shfl_xor(s, 2);
        s += __shfl_xor(s, 4); s += __shfl_xor(s, 8);
        if (q == 0) vi[f] = s;
        return;
    }
    const int s = b >> 3, t = b & 7;
    const int kbase = s * 32 + (l >> 4) * 8;
    const int c = t * 16 + (l & 15);
    short8 hi, lo;
    #pragma unroll
    for (int j = 0; j < 8; ++j) {
        const float w = Wj[(long)(kbase + j) * HID + c];
        const unsigned short h = f2b_trunc(w);
        hi[j] = (short)h;
        lo[j] = (short)f2b(w - b2f(h));
    }
    whi[b * 64 + l] = hi;
    wlo[b * 64 + l] = lo;
}

// Fused: Wh = h_i @ W_j (MFMA, split-bf16), si = h_i.vi + ab, sj = Wh.a_w[128:]
__global__ __launch_bounds__(256) void k_gemm(const float* __restrict__ hin,
                                              const short8* __restrict__ whi,
                                              const short8* __restrict__ wlo,
                                              const float* __restrict__ vi,
                                              const float* __restrict__ aw,
                                              const float* __restrict__ ab,
                                              unsigned short* __restrict__ Wh,
                                              float* __restrict__ sib,
                                              float* __restrict__ sjv) {
    const int tid  = threadIdx.x;
    const int l    = tid & 63;
    const int wave = blockIdx.x * 4 + (tid >> 6);
    if (wave >= NN / 16) return;
    const long rowbase = (long)wave * 16;
    const int r  = l & 15;
    const int kg = l >> 4;

    const float* hrow = hin + (rowbase + r) * FIN + kg * 8;
    const float* vip  = vi + kg * 8;

    f32x4 acc[8];
    #pragma unroll
    for (int t = 0; t < 8; ++t) acc[t] = (f32x4){0.f, 0.f, 0.f, 0.f};
    float si = 0.f;

    #pragma unroll
    for (int s = 0; s < 8; ++s) {
        short8 BH[8], BL[8];
        #pragma unroll
        for (int t = 0; t < 8; ++t) {
            BH[t] = whi[(s * 8 + t) * 64 + l];
            BL[t] = wlo[(s * 8 + t) * 64 + l];
        }
        const float4 ha = *(const float4*)(hrow + s * 32);
        const float4 hb = *(const float4*)(hrow + s * 32 + 4);
        const float4 va = *(const float4*)(vip + s * 32);
        const float4 vb = *(const float4*)(vip + s * 32 + 4);
        const float hv[8] = {ha.x, ha.y, ha.z, ha.w, hb.x, hb.y, hb.z, hb.w};
        const float vv[8] = {va.x, va.y, va.z, va.w, vb.x, vb.y, vb.z, vb.w};
        short8 ahi, alo;
        #pragma unroll
        for (int j = 0; j < 8; ++j) {
            si += hv[j] * vv[j];
            const unsigned short hb16 = f2b_trunc(hv[j]);
            ahi[j] = (short)hb16;
            alo[j] = (short)f2b(hv[j] - b2f(hb16));
        }
        #pragma unroll
        for (int t = 0; t < 8; ++t) {
            acc[t] = __builtin_amdgcn_mfma_f32_16x16x32_bf16(ahi, BH[t], acc[t], 0, 0, 0);
            acc[t] = __builtin_amdgcn_mfma_f32_16x16x32_bf16(alo, BH[t], acc[t], 0, 0, 0);
            acc[t] = __builtin_amdgcn_mfma_f32_16x16x32_bf16(ahi, BL[t], acc[t], 0, 0, 0);
        }
    }

    si += __shfl_xor(si, 16);
    si += __shfl_xor(si, 32);
    if (l < 16) sib[rowbase + l] = si + ab[0];

    float aw2v[8];
    #pragma unroll
    for (int t = 0; t < 8; ++t) aw2v[t] = aw[HID + t * 16 + r];
    #pragma unroll
    for (int j = 0; j < 4; ++j) {
        float p = 0.f;
        #pragma unroll
        for (int t = 0; t < 8; ++t) p += acc[t][j] * aw2v[t];
        p += __shfl_xor(p, 1); p += __shfl_xor(p, 2);
        p += __shfl_xor(p, 4); p += __shfl_xor(p, 8);
        if (r == 0) sjv[rowbase + kg * 4 + j] = p;
    }

    #pragma unroll
    for (int j = 0; j < 4; ++j) {
        const long rr = rowbase + kg * 4 + j;
        #pragma unroll
        for (int t = 0; t < 8; ++t)
            Wh[rr * HID + t * 16 + r] = f2b(acc[t][j]);
    }
}

// attn: 2 nodes per wave. Softmax per 32-lane half. Then ALL 32 (w,ic)
// pairs are shfl-precomputed, 16 independent uint4 loads issued
// back-to-back (max MLP), then pure-FMA accumulate + 2-level reduce.
__global__ __launch_bounds__(256) void k_attn(const int* __restrict__ ctx,
                                              const unsigned short* __restrict__ Wh,
                                              const float* __restrict__ sib,
                                              const float* __restrict__ sjv,
                                              float* __restrict__ out) {
    const int lane = threadIdx.x & 63;
    const long n0 = ((long)blockIdx.x * 4 + (threadIdx.x >> 6)) * 2;
    const int half = lane >> 5;          // which of the 2 nodes this lane scores
    const int c    = lane & 31;
    const long n   = n0 + half;

    const int idx = ctx[n * NCTX + c];
    const int icl = (idx >= 0) ? idx : 0;
    float s;
    if (idx >= 0) {
        s = sib[n] + sjv[icl];
        s = (s >= 0.f) ? s : 0.2f * s;
    } else {
        s = -9e15f;
    }
    float mx = s;
    #pragma unroll
    for (int m = 16; m >= 1; m >>= 1) mx = fmaxf(mx, __shfl_xor(mx, m));
    const float e = __expf(s - mx);
    float sum = e;
    #pragma unroll
    for (int m = 16; m >= 1; m >>= 1) sum += __shfl_xor(sum, m);
    const float at = (idx >= 0) ? e / sum : 0.f;

    const int rq = lane >> 4;    // 4 rows per load instruction
    const int cl = lane & 15;    // 16-B chunk within 256-B row

    // precompute all weights/indices first (VALU only, no loads in between)
    float w0[8], w1[8];
    int   i0[8], i1[8];
    #pragma unroll
    for (int i = 0; i < 8; ++i) {
        w0[i] = __shfl(at,  i * 4 + rq);
        i0[i] = __shfl(icl, i * 4 + rq);
        w1[i] = __shfl(at,  32 + i * 4 + rq);
        i1[i] = __shfl(icl, 32 + i * 4 + rq);
    }
    // issue all 16 independent loads
    uint4 L0[8], L1[8];
    #pragma unroll
    for (int i = 0; i < 8; ++i)
        L0[i] = *(const uint4*)(Wh + (long)i0[i] * HID + cl * 8);
    #pragma unroll
    for (int i = 0; i < 8; ++i)
        L1[i] = *(const uint4*)(Wh + (long)i1[i] * HID + cl * 8);

    float a[8] = {0.f,0.f,0.f,0.f,0.f,0.f,0.f,0.f};
    float b[8] = {0.f,0.f,0.f,0.f,0.f,0.f,0.f,0.f};
    #pragma unroll
    for (int i = 0; i < 8; ++i) {
        const uint4 p0 = L0[i]; const float w = w0[i];
        a[0] += w * b2f((unsigned short)(p0.x & 0xFFFFu));
        a[1] += w * b2f((unsigned short)(p0.x >> 16));
        a[2] += w * b2f((unsigned short)(p0.y & 0xFFFFu));
        a[3] += w * b2f((unsigned short)(p0.y >> 16));
        a[4] += w * b2f((unsigned short)(p0.z & 0xFFFFu));
        a[5] += w * b2f((unsigned short)(p0.z >> 16));
        a[6] += w * b2f((unsigned short)(p0.w & 0xFFFFu));
        a[7] += w * b2f((unsigned short)(p0.w >> 16));
        const uint4 p1 = L1[i]; const float v = w1[i];
        b[0] += v * b2f((unsigned short)(p1.x & 0xFFFFu));
        b[1] += v * b2f((unsigned short)(p1.x >> 16));
        b[2] += v * b2f((unsigned short)(p1.y & 0xFFFFu));
        b[3] += v * b2f((unsigned short)(p1.y >> 16));
        b[4] += v * b2f((unsigned short)(p1.z & 0xFFFFu));
        b[5] += v * b2f((unsigned short)(p1.z >> 16));
        b[6] += v * b2f((unsigned short)(p1.w & 0xFFFFu));
        b[7] += v * b2f((unsigned short)(p1.w >> 16));
    }
    // reduce over the 4 row-quarters (lane bits 4,5)
    #pragma unroll
    for (int i = 0; i < 8; ++i) {
        a[i] += __shfl_xor(a[i], 16); a[i] += __shfl_xor(a[i], 32);
        b[i] += __shfl_xor(b[i], 16); b[i] += __shfl_xor(b[i], 32);
    }
    if (lane < 16) {
        float4* op = (float4*)(out + n0 * HID + cl * 8);
        op[0] = (float4){a[0], a[1], a[2], a[3]};
        op[1] = (float4){a[4], a[5], a[6], a[7]};
    } else if (lane < 32) {
        float4* op = (float4*)(out + (n0 + 1) * HID + cl * 8);
        op[0] = (float4){b[0], b[1], b[2], b[3]};
        op[1] = (float4){b[4], b[5], b[6], b[7]};
    }
}

extern "C" void kernel_launch(void* const* d_in, const int* in_sizes, int n_in,
                              void* d_out, int out_size, void* d_ws, size_t ws_size,
                              hipStream_t stream) {
    const float* h_i = (const float*)d_in[0];
    const int*   ctx = (const int*)d_in[1];
    const float* W_i = (const float*)d_in[2];
    const float* W_j = (const float*)d_in[3];
    const float* a_w = (const float*)d_in[4];
    const float* a_b = (const float*)d_in[5];
    float* out = (float*)d_out;

    char* ws = (char*)d_ws;
    unsigned short* Wh = (unsigned short*)ws;             // N*H bf16 = 7,680,000 B
    float* sib = (float*)(ws + 7680000);                  // N f32
    float* sjv = (float*)(ws + 7800000);                  // N f32
    float* vi  = (float*)(ws + 7920000);                  // 256 f32
    short8* whi = (short8*)(ws + 7921024);                // 64 KB
    short8* wlo = (short8*)(ws + 7986560);                // 64 KB

    k_pack<<<128, 64, 0, stream>>>(W_j, W_i, a_w, whi, wlo, vi);
    k_gemm<<<(NN / 16 + 3) / 4, 256, 0, stream>>>(h_i, whi, wlo, vi, a_w, a_b, Wh, sib, sjv);
    k_attn<<<NN / 8, 256, 0, stream>>>(ctx, Wh, sib, sjv, out);
}

// Round 10
// 52.904 us; speedup vs baseline: 1.0248x; 1.0248x over previous
//
#include <hip/hip_runtime.h>

#define NN   30000
#define NCTX 32
#define FIN  256
#define HID  128

typedef short short8 __attribute__((ext_vector_type(8)));
typedef float f32x4  __attribute__((ext_vector_type(4)));
typedef _Float16 half2v __attribute__((ext_vector_type(2)));

#define SEL_LO 0x01000504u   // {A.hw0, B.hw0} (consistent for values & weights)
#define SEL_HI 0x03020706u   // {A.hw1, B.hw1}

__device__ __forceinline__ unsigned short f2b(float x) {   // RTNE bf16
    union { float f; unsigned u; } v; v.f = x;
    unsigned r = v.u + 0x7FFFu + ((v.u >> 16) & 1u);
    return (unsigned short)(r >> 16);
}
__device__ __forceinline__ unsigned short f2b_trunc(float x) {
    union { float f; unsigned u; } v; v.f = x;
    return (unsigned short)(v.u >> 16);
}
__device__ __forceinline__ float b2f(unsigned short u) {
    union { unsigned u; float f; } v; v.u = ((unsigned)u) << 16;
    return v.f;
}
__device__ __forceinline__ unsigned short f2h(float x) {   // f32 -> f16 RTNE bits
    const _Float16 h = (_Float16)x;
    return __builtin_bit_cast(unsigned short, h);
}
__device__ __forceinline__ float dot2(unsigned vp, unsigned wp, float acc) {
    return __builtin_amdgcn_fdot2(__builtin_bit_cast(half2v, vp),
                                  __builtin_bit_cast(half2v, wp), acc, false);
}

// Blocks 0-63: pack W_j into MFMA B-fragment order (split bf16 hi/lo).
// Blocks 64-127: vi[f] = Wi[f,:].aw  (quarter-wave per feature, coalesced).
__global__ __launch_bounds__(64) void k_pack(const float* __restrict__ Wj,
                                             const float* __restrict__ Wi,
                                             const float* __restrict__ aw,
                                             short8* __restrict__ whi,
                                             short8* __restrict__ wlo,
                                             float* __restrict__ vi) {
    const int b = blockIdx.x;
    const int l = threadIdx.x;
    if (b >= 64) {
        const int fi = l >> 4;
        const int q  = l & 15;
        const int f  = (b - 64) * 4 + fi;
        const float4 w0 = *(const float4*)(Wi + (long)f * HID + q * 8);
        const float4 w1 = *(const float4*)(Wi + (long)f * HID + q * 8 + 4);
        const float4 a0 = *(const float4*)(aw + q * 8);
        const float4 a1 = *(const float4*)(aw + q * 8 + 4);
        float s = w0.x * a0.x + w0.y * a0.y + w0.z * a0.z + w0.w * a0.w
                + w1.x * a1.x + w1.y * a1.y + w1.z * a1.z + w1.w * a1.w;
        s += __shfl_xor(s, 1); s += __shfl_xor(s, 2);
        s += __shfl_xor(s, 4); s += __shfl_xor(s, 8);
        if (q == 0) vi[f] = s;
        return;
    }
    const int s = b >> 3, t = b & 7;
    const int kbase = s * 32 + (l >> 4) * 8;
    const int c = t * 16 + (l & 15);
    short8 hi, lo;
    #pragma unroll
    for (int j = 0; j < 8; ++j) {
        const float w = Wj[(long)(kbase + j) * HID + c];
        const unsigned short h = f2b_trunc(w);
        hi[j] = (short)h;
        lo[j] = (short)f2b(w - b2f(h));
    }
    whi[b * 64 + l] = hi;
    wlo[b * 64 + l] = lo;
}

// Fused: Wh = h_i @ W_j (MFMA, split-bf16), si = h_i.vi + ab, sj = Wh.a_w[128:]
// Table Wh is stored as f16 (RTNE) for the dot2-based attn kernel.
__global__ __launch_bounds__(256) void k_gemm(const float* __restrict__ hin,
                                              const short8* __restrict__ whi,
                                              const short8* __restrict__ wlo,
                                              const float* __restrict__ vi,
                                              const float* __restrict__ aw,
                                              const float* __restrict__ ab,
                                              unsigned short* __restrict__ Wh,
                                              float* __restrict__ sib,
                                              float* __restrict__ sjv) {
    const int tid  = threadIdx.x;
    const int l    = tid & 63;
    const int wave = blockIdx.x * 4 + (tid >> 6);
    if (wave >= NN / 16) return;
    const long rowbase = (long)wave * 16;
    const int r  = l & 15;
    const int kg = l >> 4;

    const float* hrow = hin + (rowbase + r) * FIN + kg * 8;
    const float* vip  = vi + kg * 8;

    f32x4 acc[8];
    #pragma unroll
    for (int t = 0; t < 8; ++t) acc[t] = (f32x4){0.f, 0.f, 0.f, 0.f};
    float si = 0.f;

    #pragma unroll
    for (int s = 0; s < 8; ++s) {
        short8 BH[8], BL[8];
        #pragma unroll
        for (int t = 0; t < 8; ++t) {
            BH[t] = whi[(s * 8 + t) * 64 + l];
            BL[t] = wlo[(s * 8 + t) * 64 + l];
        }
        const float4 ha = *(const float4*)(hrow + s * 32);
        const float4 hb = *(const float4*)(hrow + s * 32 + 4);
        const float4 va = *(const float4*)(vip + s * 32);
        const float4 vb = *(const float4*)(vip + s * 32 + 4);
        const float hv[8] = {ha.x, ha.y, ha.z, ha.w, hb.x, hb.y, hb.z, hb.w};
        const float vv[8] = {va.x, va.y, va.z, va.w, vb.x, vb.y, vb.z, vb.w};
        short8 ahi, alo;
        #pragma unroll
        for (int j = 0; j < 8; ++j) {
            si += hv[j] * vv[j];
            const unsigned short hb16 = f2b_trunc(hv[j]);
            ahi[j] = (short)hb16;
            alo[j] = (short)f2b(hv[j] - b2f(hb16));
        }
        #pragma unroll
        for (int t = 0; t < 8; ++t) {
            acc[t] = __builtin_amdgcn_mfma_f32_16x16x32_bf16(ahi, BH[t], acc[t], 0, 0, 0);
            acc[t] = __builtin_amdgcn_mfma_f32_16x16x32_bf16(alo, BH[t], acc[t], 0, 0, 0);
            acc[t] = __builtin_amdgcn_mfma_f32_16x16x32_bf16(ahi, BL[t], acc[t], 0, 0, 0);
        }
    }

    si += __shfl_xor(si, 16);
    si += __shfl_xor(si, 32);
    if (l < 16) sib[rowbase + l] = si + ab[0];

    float aw2v[8];
    #pragma unroll
    for (int t = 0; t < 8; ++t) aw2v[t] = aw[HID + t * 16 + r];
    #pragma unroll
    for (int j = 0; j < 4; ++j) {
        float p = 0.f;
        #pragma unroll
        for (int t = 0; t < 8; ++t) p += acc[t][j] * aw2v[t];
        p += __shfl_xor(p, 1); p += __shfl_xor(p, 2);
        p += __shfl_xor(p, 4); p += __shfl_xor(p, 8);
        if (r == 0) sjv[rowbase + kg * 4 + j] = p;
    }

    #pragma unroll
    for (int j = 0; j < 4; ++j) {
        const long rr = rowbase + kg * 4 + j;
        #pragma unroll
        for (int t = 0; t < 8; ++t)
            Wh[rr * HID + t * 16 + r] = f2h(acc[t][j]);
    }
}

// per-node softmax + gather-aggregate, f16 table + v_dot2_f32_f16 core.
// Quarter-wave per row; contexts paired (c, c+4): per word-pair
// 2 v_perm + 2 dot2 replace 4 unpacks + 4 FMAs.
__global__ __launch_bounds__(256) void k_attn(const int* __restrict__ ctx,
                                              const unsigned short* __restrict__ Wh,
                                              const float* __restrict__ sib,
                                              const float* __restrict__ sjv,
                                              float* __restrict__ out) {
    const int lane = threadIdx.x & 63;
    const long n = (long)blockIdx.x * 4 + (threadIdx.x >> 6);
    const int c = lane & 31;
    const int idx = ctx[n * NCTX + c];
    const int icl = (idx >= 0) ? idx : 0;
    float s;
    if (idx >= 0) {
        s = sib[n] + sjv[icl];
        s = (s >= 0.f) ? s : 0.2f * s;
    } else {
        s = -9e15f;
    }
    float mx = s;
    #pragma unroll
    for (int m = 16; m >= 1; m >>= 1) mx = fmaxf(mx, __shfl_xor(mx, m));
    const float e = __expf(s - mx);
    float sum = e;
    #pragma unroll
    for (int m = 16; m >= 1; m >>= 1) sum += __shfl_xor(sum, m);
    const float at = (idx >= 0) ? e / sum : 0.f;

    const int q  = lane >> 4;              // row-quarter
    const unsigned coff = (lane & 15) * 16; // byte offset of 16-B chunk in 256-B row
    const char* base = (const char*)Wh;

    float a[8] = {0.f,0.f,0.f,0.f,0.f,0.f,0.f,0.f};
    #pragma unroll
    for (int p = 0; p < 4; ++p) {
        const float wA = __shfl(at,  p * 8 + q);
        const int   iA = __shfl(icl, p * 8 + q);
        const float wB = __shfl(at,  p * 8 + 4 + q);
        const int   iB = __shfl(icl, p * 8 + 4 + q);
        const uint4 uA = *(const uint4*)(base + (((unsigned)iA << 8) | coff));
        const uint4 uB = *(const uint4*)(base + (((unsigned)iB << 8) | coff));
        const unsigned hA = (unsigned)f2h(wA);
        const unsigned hB = (unsigned)f2h(wB);
        const unsigned wp = __builtin_amdgcn_perm(hA, hB, SEL_LO);
        a[0] = dot2(__builtin_amdgcn_perm(uA.x, uB.x, SEL_LO), wp, a[0]);
        a[1] = dot2(__builtin_amdgcn_perm(uA.x, uB.x, SEL_HI), wp, a[1]);
        a[2] = dot2(__builtin_amdgcn_perm(uA.y, uB.y, SEL_LO), wp, a[2]);
        a[3] = dot2(__builtin_amdgcn_perm(uA.y, uB.y, SEL_HI), wp, a[3]);
        a[4] = dot2(__builtin_amdgcn_perm(uA.z, uB.z, SEL_LO), wp, a[4]);
        a[5] = dot2(__builtin_amdgcn_perm(uA.z, uB.z, SEL_HI), wp, a[5]);
        a[6] = dot2(__builtin_amdgcn_perm(uA.w, uB.w, SEL_LO), wp, a[6]);
        a[7] = dot2(__builtin_amdgcn_perm(uA.w, uB.w, SEL_HI), wp, a[7]);
    }
    #pragma unroll
    for (int i = 0; i < 8; ++i) {
        a[i] += __shfl_xor(a[i], 16);
        a[i] += __shfl_xor(a[i], 32);
    }
    if (lane < 16) {
        float4* op = (float4*)(out + n * HID + (coff >> 2) * 2);
        op[0] = (float4){a[0], a[1], a[2], a[3]};
        op[1] = (float4){a[4], a[5], a[6], a[7]};
    }
}

extern "C" void kernel_launch(void* const* d_in, const int* in_sizes, int n_in,
                              void* d_out, int out_size, void* d_ws, size_t ws_size,
                              hipStream_t stream) {
    const float* h_i = (const float*)d_in[0];
    const int*   ctx = (const int*)d_in[1];
    const float* W_i = (const float*)d_in[2];
    const float* W_j = (const float*)d_in[3];
    const float* a_w = (const float*)d_in[4];
    const float* a_b = (const float*)d_in[5];
    float* out = (float*)d_out;

    char* ws = (char*)d_ws;
    unsigned short* Wh = (unsigned short*)ws;             // N*H f16 = 7,680,000 B
    float* sib = (float*)(ws + 7680000);                  // N f32
    float* sjv = (float*)(ws + 7800000);                  // N f32
    float* vi  = (float*)(ws + 7920000);                  // 256 f32
    short8* whi = (short8*)(ws + 7921024);                // 64 KB
    short8* wlo = (short8*)(ws + 7986560);                // 64 KB

    k_pack<<<128, 64, 0, stream>>>(W_j, W_i, a_w, whi, wlo, vi);
    k_gemm<<<(NN / 16 + 3) / 4, 256, 0, stream>>>(h_i, whi, wlo, vi, a_w, a_b, Wh, sib, sjv);
    k_attn<<<NN / 4, 256, 0, stream>>>(ctx, Wh, sib, sjv, out);
}